// Round 6
// baseline (509.521 us; speedup 1.0000x reference)
//
#include <hip/hip_runtime.h>
#include <math.h>

#define Nn 100000
#define Ee 500000
#define Dd 128
#define Rr 10
#define ND (Nn * Dd)
#define SCAN_CHUNK 1024
#define NBLK ((Nn + SCAN_CHUNK - 1) / SCAN_CHUNK)   // 98
#define LDK 136   // padded LDS row stride (fp16 elems)
#define EPSF 1e-5f
#define XBLK (ND / 8 / 256)   // 6250

typedef _Float16 half_t;
typedef __attribute__((ext_vector_type(8))) _Float16 half8;
typedef __attribute__((ext_vector_type(4))) float f32x4;
typedef unsigned short ushort;
typedef unsigned int uint;
typedef unsigned long long u64;

union H4 { u64 u; _Float16 h[4]; };
union H8 { uint4 q; _Float16 h[8]; };

__device__ __forceinline__ void atomAddF(float* p, float v) {
    unsafeAtomicAdd(p, v);   // HW global_atomic_add_f32
}

// ---------------- zero fill ----------------
__global__ void kzeroi(int* p, int n) {
    int i = blockIdx.x * blockDim.x + threadIdx.x;
    int stride = gridDim.x * blockDim.x;
    for (; i < n; i += stride) p[i] = 0;
}

// ---------------- CSR build ----------------
__global__ void khist(const int* __restrict__ src, const int* __restrict__ dst,
                      int* cnt_s, int* cnt_d, int ne) {
    int e = blockIdx.x * blockDim.x + threadIdx.x;
    if (e < ne) {
        atomicAdd(&cnt_s[src[e]], 1);
        atomicAdd(&cnt_d[dst[e]], 1);
    }
}

// dual-direction local scan + dinv
__global__ __launch_bounds__(256) void kscan1(
    const int* __restrict__ cnt_s, const int* __restrict__ cnt_d,
    int* off_s, int* off_d, int* bsum_s, int* bsum_d,
    float* dinv_s, float* dinv_d) {
    int dir = blockIdx.x >= NBLK;
    int lb = blockIdx.x - dir * NBLK;
    const int* cnt = dir ? cnt_d : cnt_s;
    int* off = dir ? off_d : off_s;
    int* bsum = dir ? bsum_d : bsum_s;
    float* dinv = dir ? dinv_d : dinv_s;
    __shared__ int s[256];
    int tid = threadIdx.x;
    int base = lb * SCAN_CHUNK + tid * 4;
    int v[4], sum = 0;
#pragma unroll
    for (int q = 0; q < 4; q++) {
        int c = (base + q < Nn) ? cnt[base + q] : 0;
        v[q] = c;
        sum += c;
        if (base + q < Nn) dinv[base + q] = (c > 0) ? rsqrtf((float)c) : 0.f;
    }
    s[tid] = sum;
    __syncthreads();
#pragma unroll
    for (int ofs = 1; ofs < 256; ofs <<= 1) {
        int t = (tid >= ofs) ? s[tid - ofs] : 0;
        __syncthreads();
        s[tid] += t;
        __syncthreads();
    }
    if (tid == 255) bsum[lb] = s[255];
    int run = s[tid] - sum;
#pragma unroll
    for (int q = 0; q < 4; q++) {
        if (base + q < Nn) off[base + q] = run;
        run += v[q];
    }
}

__global__ __launch_bounds__(128) void kscan2(int* bsum_s, int* bsum_d,
                                              int* off_s, int* off_d) {
    int dir = blockIdx.x;
    int* bsum = dir ? bsum_d : bsum_s;
    int* off = dir ? off_d : off_s;
    __shared__ int s[128];
    int tid = threadIdx.x;
    int v = (tid < NBLK) ? bsum[tid] : 0;
    s[tid] = v;
    __syncthreads();
#pragma unroll
    for (int ofs = 1; ofs < 128; ofs <<= 1) {
        int t = (tid >= ofs) ? s[tid - ofs] : 0;
        __syncthreads();
        s[tid] += t;
        __syncthreads();
    }
    if (tid < NBLK) bsum[tid] = s[tid] - v;
    if (tid == 127) off[Nn] = s[127];
}

__global__ void kscan3(int* off_s, int* off_d, const int* __restrict__ bsum_s,
                       const int* __restrict__ bsum_d, int* cur_s, int* cur_d) {
    int idx = blockIdx.x * blockDim.x + threadIdx.x;
    if (idx >= 2 * Nn) return;
    int dir = idx >= Nn;
    int i = idx - dir * Nn;
    int* off = dir ? off_d : off_s;
    const int* bsum = dir ? bsum_d : bsum_s;
    int* cur = dir ? cur_d : cur_s;
    int o = off[i] + bsum[i >> 10];
    off[i] = o;
    cur[i] = o;
}

// interleaved edge record: low32 = (nbr<<4)|type, high32 = norm bits
__global__ void kscatter(const int* __restrict__ src, const int* __restrict__ dst,
                         const int* __restrict__ typ,
                         const float* __restrict__ dinv_s, const float* __restrict__ dinv_d,
                         int* cur_s, int* cur_d,
                         u64* rec_s, u64* rec_d, int ne) {
    int e = blockIdx.x * blockDim.x + threadIdx.x;
    if (e >= ne) return;
    int s = src[e], d = dst[e], t = typ[e];
    int ps = atomicAdd(&cur_s[s], 1);
    rec_s[ps] = (u64)(uint)((d << 4) | t) |
                ((u64)__float_as_uint(dinv_s[s] * dinv_s[d]) << 32);
    int pd = atomicAdd(&cur_d[d], 1);
    rec_d[pd] = (u64)(uint)((s << 4) | t) |
                ((u64)__float_as_uint(dinv_d[d] * dinv_d[s]) << 32);
}

// ---------------- mega-prep: x cast | W cast (both layers) | rel chain | rel0 pad ------
__global__ __launch_bounds__(256) void kprep(
    const float* __restrict__ x, const float* __restrict__ lr0,
    const float* __restrict__ w_in, const float* __restrict__ w_out,
    const float* __restrict__ w_loop, const float* __restrict__ w_rel,
    const float* __restrict__ r0,
    half_t* __restrict__ xb, half_t* __restrict__ xlb,
    half_t* __restrict__ Wt, float* __restrict__ rel0p, float* __restrict__ rel1p,
    float* __restrict__ r2out) {
    int blk = blockIdx.x;
    int tid = threadIdx.x;
    if (blk < XBLK) {
        // xb = f16(x0), xlb = f16(x0 * looprel0)
        int idx = blk * 256 + tid;
        int base = idx * 8;
        int k = base & 127;
        float4 v0 = *(const float4*)(x + base);
        float4 v1 = *(const float4*)(x + base + 4);
        float4 l0 = *(const float4*)(lr0 + k);
        float4 l1 = *(const float4*)(lr0 + k + 4);
        H8 xo, xl;
        xo.h[0] = (half_t)v0.x; xo.h[1] = (half_t)v0.y; xo.h[2] = (half_t)v0.z; xo.h[3] = (half_t)v0.w;
        xo.h[4] = (half_t)v1.x; xo.h[5] = (half_t)v1.y; xo.h[6] = (half_t)v1.z; xo.h[7] = (half_t)v1.w;
        xl.h[0] = (half_t)(v0.x * l0.x); xl.h[1] = (half_t)(v0.y * l0.y);
        xl.h[2] = (half_t)(v0.z * l0.z); xl.h[3] = (half_t)(v0.w * l0.w);
        xl.h[4] = (half_t)(v1.x * l1.x); xl.h[5] = (half_t)(v1.y * l1.y);
        xl.h[6] = (half_t)(v1.z * l1.z); xl.h[7] = (half_t)(v1.w * l1.w);
        *(uint4*)(xb + base) = xo.q;
        *(uint4*)(xlb + base) = xl.q;
    } else if (blk < XBLK + 384) {
        // Wt[l][p][n][k] = f16(W[l,p][k][n]) for both layers
        int idx = (blk - XBLK) * 256 + tid;   // 0..98303
        int l = idx >= 49152;
        int rem = idx - l * 49152;
        int p = rem >> 14, ri = rem & 16383;
        int n = ri >> 7, k = ri & 127;
        const float* W = (p == 0) ? (w_in + l * 16384)
                       : ((p == 1) ? (w_out + l * 16384) : (w_loop + l * 16384));
        Wt[idx] = (half_t)W[k * 128 + n];
    } else if (blk == XBLK + 384) {
        // rel chain: rel1p(rows 0..9) = r0 @ w_rel[0], pad 10..15 = 0; r2out = r1 @ w_rel[1]
        __shared__ float sr[Rr * Dd];
        for (int i = tid; i < Rr * Dd; i += 256) sr[i] = r0[i];
        __syncthreads();
        for (int ph = 0; ph < 2; ph++) {
            const float* w = w_rel + ph * 16384;
            float o[5];
#pragma unroll
            for (int q = 0; q < 5; q++) {
                int oi = tid + q * 256;
                int row = oi >> 7, j = oi & 127;
                float acc = 0.f;
                for (int k = 0; k < 128; k++) acc += sr[row * 128 + k] * w[k * 128 + j];
                o[q] = acc;
            }
            __syncthreads();
            float* dst = ph ? r2out : rel1p;
#pragma unroll
            for (int q = 0; q < 5; q++) {
                int oi = tid + q * 256;
                sr[oi] = o[q];
                dst[oi] = o[q];
            }
            __syncthreads();
        }
        for (int i = Rr * Dd + tid; i < 16 * Dd; i += 256) rel1p[i] = 0.f;
    } else {
        // rel0p: rows 0..9 = r0, rows 10..15 = 0
        for (int i = tid; i < 16 * Dd; i += 256) rel0p[i] = (i < Rr * Dd) ? r0[i] : 0.f;
    }
}

// ---------------- gather v3: 2 nodes/wave, 8B/lane, batch-8 record preload ----------------
__global__ __launch_bounds__(256) void kgather(
    const int* __restrict__ off_s, const u64* __restrict__ rec_s,
    const int* __restrict__ off_d, const u64* __restrict__ rec_d,
    const half_t* __restrict__ xb, const float* __restrict__ relp,
    half_t* __restrict__ aggin, half_t* __restrict__ aggout, int gb) {
    int blk = blockIdx.x;
    const int* off; const u64* rec; half_t* agg;
    if (blk < gb) { off = off_s; rec = rec_s; agg = aggin; }
    else { blk -= gb; off = off_d; rec = rec_d; agg = aggout; }
    int wv = threadIdx.x >> 6;
    int lane = threadIdx.x & 63;
    int hf = lane >> 5;        // which node of the pair
    int hl = lane & 31;        // 8-byte chunk within row
    int node = blk * 8 + wv * 2 + hf;
    bool valid = node < Nn;
    int nodec = valid ? node : (Nn - 1);
    int b = off[nodec];
    int e = off[nodec + 1];
    int n_it = valid ? (e - b) : 0;
    int other = __shfl(n_it, lane ^ 32, 64);
    int mx = n_it > other ? n_it : other;    // wave-uniform-ish loop bound (per pair)

    const u64* x4 = (const u64*)xb;
    const float4* r4 = (const float4*)relp;
    float a0 = 0.f, a1 = 0.f, a2 = 0.f, a3 = 0.f;

    for (int it0 = 0; it0 < mx; it0 += 8) {
        u64 rr[8];
#pragma unroll
        for (int q = 0; q < 8; q++) rr[q] = rec[b + it0 + q];   // contiguous, independent
        H4 xv[8]; float4 rl[8]; float wq[8];
#pragma unroll
        for (int q = 0; q < 8; q++) {
            uint p = (uint)rr[q];
            uint nmb = (uint)(rr[q] >> 32);
            bool c = (it0 + q) < n_it;
            wq[q] = c ? __uint_as_float(nmb) : 0.f;
            int xi = c ? (int)(p >> 4) : 0;          // inactive -> row 0 (L2-hot)
            xv[q].u = x4[(size_t)xi * 32 + hl];
            rl[q] = r4[(p & 15u) * 32 + hl];         // relp padded to 16 rows
        }
#pragma unroll
        for (int q = 0; q < 8; q++) {
            a0 += (float)xv[q].h[0] * rl[q].x * wq[q];
            a1 += (float)xv[q].h[1] * rl[q].y * wq[q];
            a2 += (float)xv[q].h[2] * rl[q].z * wq[q];
            a3 += (float)xv[q].h[3] * rl[q].w * wq[q];
        }
    }
    if (valid) {
        H4 o;
        o.h[0] = (half_t)a0; o.h[1] = (half_t)a1;
        o.h[2] = (half_t)a2; o.h[3] = (half_t)a3;
        ((u64*)agg)[(size_t)node * 32 + hl] = o.u;
    }
}

// ---------------- MFMA GEMM + bias + BN col stats, fp16 out ----------------
__global__ __launch_bounds__(256) void kmm(
    const half_t* __restrict__ aggin, const half_t* __restrict__ aggout,
    const half_t* __restrict__ xlb, const half_t* __restrict__ Wt,
    const float* __restrict__ bias, half_t* __restrict__ out,
    float* colsum, float* colsumsq) {
    __shared__ half_t sW[128 * LDK];
    const int tid = threadIdx.x;
    const int wv = tid >> 6;
    const int lane = tid & 63;
    const int col = lane & 15;
    const int quad = lane >> 4;
    const int m0 = blockIdx.x * 128;
    const int rowbase = m0 + wv * 32;

    f32x4 acc[2][8];
#pragma unroll
    for (int m = 0; m < 2; m++)
#pragma unroll
        for (int j = 0; j < 8; j++) acc[m][j] = (f32x4){0.f, 0.f, 0.f, 0.f};

    const half_t* Ap[3] = {aggin, aggout, xlb};
    int r0 = rowbase + col;
    int r1 = r0 + 16;
    int r0c = (r0 < Nn) ? r0 : (Nn - 1);
    int r1c = (r1 < Nn) ? r1 : (Nn - 1);

    for (int p = 0; p < 3; p++) {
        __syncthreads();
        {
            const half8* Wg = (const half8*)(Wt + p * 16384);
#pragma unroll
            for (int i = 0; i < 8; i++) {
                int c = tid + i * 256;
                int n = c >> 4, ko = (c & 15) * 8;
                *(half8*)(sW + n * LDK + ko) = Wg[c];
            }
        }
        __syncthreads();
        const half_t* A = Ap[p];
#pragma unroll
        for (int s = 0; s < 4; s++) {
            int ko = s * 32 + quad * 8;
            half8 va0 = *(const half8*)(A + r0c * Dd + ko);
            half8 va1 = *(const half8*)(A + r1c * Dd + ko);
#pragma unroll
            for (int j = 0; j < 8; j++) {
                half8 vb = *(const half8*)(sW + (j * 16 + col) * LDK + ko);
                acc[0][j] = __builtin_amdgcn_mfma_f32_16x16x32_f16(va0, vb, acc[0][j], 0, 0, 0);
                acc[1][j] = __builtin_amdgcn_mfma_f32_16x16x32_f16(va1, vb, acc[1][j], 0, 0, 0);
            }
        }
    }

    const float inv3 = 1.f / 3.f;
    float bcol[8], sum[8], ssq[8];
#pragma unroll
    for (int j = 0; j < 8; j++) {
        bcol[j] = bias[j * 16 + col];
        sum[j] = 0.f; ssq[j] = 0.f;
    }
#pragma unroll
    for (int m = 0; m < 2; m++) {
        int rb = rowbase + m * 16;
        if (rb < Nn) {
#pragma unroll
            for (int j = 0; j < 8; j++) {
#pragma unroll
                for (int r = 0; r < 4; r++) {
                    float v = acc[m][j][r] * inv3 + bcol[j];
                    out[(rb + quad * 4 + r) * Dd + j * 16 + col] = (half_t)v;
                    sum[j] += v;
                    ssq[j] += v * v;
                }
            }
        }
    }
#pragma unroll
    for (int j = 0; j < 8; j++) {
        sum[j] += __shfl_xor(sum[j], 16, 64);
        sum[j] += __shfl_xor(sum[j], 32, 64);
        ssq[j] += __shfl_xor(ssq[j], 16, 64);
        ssq[j] += __shfl_xor(ssq[j], 32, 64);
    }
    __syncthreads();
    float* sred = (float*)sW;
    if (quad == 0) {
#pragma unroll
        for (int j = 0; j < 8; j++) {
            sred[wv * 128 + j * 16 + col] = sum[j];
            sred[512 + wv * 128 + j * 16 + col] = ssq[j];
        }
    }
    __syncthreads();
    if (tid < 128) {
        float s = 0.f, s2 = 0.f;
#pragma unroll
        for (int w = 0; w < 4; w++) {
            s += sred[w * 128 + tid];
            s2 += sred[512 + w * 128 + tid];
        }
        atomAddF(&colsum[tid], s);
        atomAddF(&colsumsq[tid], s2);
    }
}

// ---------------- norm+tanh layer0 (stats inline): write fp16 xb, xlb ----------------
__global__ __launch_bounds__(256) void knorm0(const half_t* __restrict__ outh,
                                              const float* __restrict__ colsum,
                                              const float* __restrict__ colsumsq,
                                              const float* __restrict__ lr,
                                              half_t* __restrict__ xb,
                                              half_t* __restrict__ xlb) {
    __shared__ float sm[128], srs[128];
    int tid = threadIdx.x;
    if (tid < 128) {
        float m = colsum[tid] * (1.f / (float)Nn);
        float v = colsumsq[tid] * (1.f / (float)Nn) - m * m;
        sm[tid] = m;
        srs[tid] = rsqrtf(v + EPSF);
    }
    __syncthreads();
    int idx = blockIdx.x * 256 + tid;
    int base = idx * 8;
    int k = base & 127;
    H8 v; v.q = *(const uint4*)(outh + base);
    H8 xo, xl;
#pragma unroll
    for (int q = 0; q < 8; q++) {
        float t = tanhf(((float)v.h[q] - sm[k + q]) * srs[k + q]);
        xo.h[q] = (half_t)t;
        xl.h[q] = (half_t)(t * lr[k + q]);
    }
    *(uint4*)(xb + base) = xo.q;
    *(uint4*)(xlb + base) = xl.q;
}

// ---------------- norm+tanh layer1 (stats inline): write fp32 final ----------------
__global__ __launch_bounds__(256) void knorm1(const half_t* __restrict__ outh,
                                              const float* __restrict__ colsum,
                                              const float* __restrict__ colsumsq,
                                              float* __restrict__ xn) {
    __shared__ float sm[128], srs[128];
    int tid = threadIdx.x;
    if (tid < 128) {
        float m = colsum[tid] * (1.f / (float)Nn);
        float v = colsumsq[tid] * (1.f / (float)Nn) - m * m;
        sm[tid] = m;
        srs[tid] = rsqrtf(v + EPSF);
    }
    __syncthreads();
    int idx = blockIdx.x * 256 + tid;
    int base = idx * 8;
    int k = base & 127;
    H8 v; v.q = *(const uint4*)(outh + base);
    float4 o0, o1;
    o0.x = tanhf(((float)v.h[0] - sm[k + 0]) * srs[k + 0]);
    o0.y = tanhf(((float)v.h[1] - sm[k + 1]) * srs[k + 1]);
    o0.z = tanhf(((float)v.h[2] - sm[k + 2]) * srs[k + 2]);
    o0.w = tanhf(((float)v.h[3] - sm[k + 3]) * srs[k + 3]);
    o1.x = tanhf(((float)v.h[4] - sm[k + 4]) * srs[k + 4]);
    o1.y = tanhf(((float)v.h[5] - sm[k + 5]) * srs[k + 5]);
    o1.z = tanhf(((float)v.h[6] - sm[k + 6]) * srs[k + 6]);
    o1.w = tanhf(((float)v.h[7] - sm[k + 7]) * srs[k + 7]);
    *(float4*)(xn + base) = o0;
    *(float4*)(xn + base + 4) = o1;
}

extern "C" void kernel_launch(void* const* d_in, const int* in_sizes, int n_in,
                              void* d_out, int out_size, void* d_ws, size_t ws_size,
                              hipStream_t stream) {
    const float* x0      = (const float*)d_in[0];
    const float* r0      = (const float*)d_in[1];
    const float* w_in    = (const float*)d_in[2];
    const float* w_out   = (const float*)d_in[3];
    const float* w_loop  = (const float*)d_in[4];
    const float* w_rel   = (const float*)d_in[5];
    const float* looprel = (const float*)d_in[6];
    const float* bias    = (const float*)d_in[7];
    const int* esrc = (const int*)d_in[8];
    const int* edst = (const int*)d_in[9];
    const int* etyp = (const int*)d_in[10];
    float* outp = (float*)d_out;

    // half region (16B-aligned base)
    half_t* us = (half_t*)d_ws;
    half_t* aggin_h  = us;                        // ND
    half_t* aggout_h = us + (size_t)ND;           // ND
    half_t* xb       = us + 2 * (size_t)ND;       // ND
    half_t* xlb      = us + 3 * (size_t)ND;       // ND
    half_t* outh     = us + 4 * (size_t)ND;       // ND
    half_t* Wt       = us + 5 * (size_t)ND;       // 2*49152
    // u64 records (8B-aligned: 5*ND+98304 halves = even)
    u64* rec_s = (u64*)(us + 5 * (size_t)ND + 2 * 49152);   // Ee+64
    u64* rec_d = rec_s + (Ee + 64);                          // Ee+64
    // float region
    float* fp = (float*)(rec_d + (Ee + 64));
    float* dinv_s  = fp;   fp += Nn;
    float* dinv_d  = fp;   fp += Nn;
    float* rel0p   = fp;   fp += 16 * Dd;
    float* rel1p   = fp;   fp += 16 * Dd;
    // int region (zero block: cnt_s, cnt_d, colsums A+B contiguous)
    int* ip = (int*)fp;
    int* cnt_s  = ip;  ip += Nn;
    int* cnt_d  = ip;  ip += Nn;
    float* colsumA = (float*)ip;  ip += 2 * Dd;
    float* colsumB = (float*)ip;  ip += 2 * Dd;
    int* off_s  = ip;  ip += Nn + 1;
    int* off_d  = ip;  ip += Nn + 1;
    int* cur_s  = ip;  ip += Nn;
    int* cur_d  = ip;  ip += Nn;
    int* bsum_s = ip;  ip += 128;
    int* bsum_d = ip;  ip += 128;

    // 1: zero cnt_s+cnt_d+colsumA+colsumB
    kzeroi<<<256, 256, 0, stream>>>(cnt_s, 2 * Nn + 4 * Dd);
    // 2: histogram
    khist<<<(Ee + 255) / 256, 256, 0, stream>>>(esrc, edst, cnt_s, cnt_d, Ee);
    // 3-5: dual scans (+dinv, +cursor copy)
    kscan1<<<2 * NBLK, 256, 0, stream>>>(cnt_s, cnt_d, off_s, off_d, bsum_s, bsum_d,
                                         dinv_s, dinv_d);
    kscan2<<<2, 128, 0, stream>>>(bsum_s, bsum_d, off_s, off_d);
    kscan3<<<(2 * Nn + 255) / 256, 256, 0, stream>>>(off_s, off_d, bsum_s, bsum_d,
                                                     cur_s, cur_d);
    // 6: CSR scatter (interleaved u64 records)
    kscatter<<<(Ee + 255) / 256, 256, 0, stream>>>(esrc, edst, etyp, dinv_s, dinv_d,
                                                   cur_s, cur_d, rec_s, rec_d, Ee);
    // 7: mega-prep
    kprep<<<XBLK + 384 + 2, 256, 0, stream>>>(
        x0, looprel, w_in, w_out, w_loop, w_rel, r0,
        xb, xlb, Wt, rel0p, rel1p, outp + (size_t)ND);

    const int gb = (Nn + 7) / 8;
    for (int l = 0; l < 2; l++) {
        const float* relp = l ? rel1p : rel0p;
        float* cs = l ? colsumB : colsumA;
        kgather<<<2 * gb, 256, 0, stream>>>(off_s, rec_s, off_d, rec_d,
                                            xb, relp, aggin_h, aggout_h, gb);
        kmm<<<(Nn + 127) / 128, 256, 0, stream>>>(aggin_h, aggout_h, xlb, Wt + l * 49152,
                                                  bias + l * Dd, outh, cs, cs + Dd);
        if (l == 0) {
            knorm0<<<ND / 8 / 256, 256, 0, stream>>>(outh, cs, cs + Dd, looprel + Dd, xb, xlb);
        } else {
            knorm1<<<ND / 8 / 256, 256, 0, stream>>>(outh, cs, cs + Dd, outp);
        }
    }
}

// Round 7
// 453.010 us; speedup vs baseline: 1.1247x; 1.1247x over previous
//
#include <hip/hip_runtime.h>
#include <math.h>

#define Nn 100000
#define Ee 500000
#define Dd 128
#define Rr 10
#define ND (Nn * Dd)
#define SCAN_CHUNK 1024
#define NBLK ((Nn + SCAN_CHUNK - 1) / SCAN_CHUNK)   // 98
#define LDK 136   // padded LDS row stride (fp16 elems)
#define EPSF 1e-5f
#define XBLK (ND / 8 / 256)   // 6250

typedef _Float16 half_t;
typedef __attribute__((ext_vector_type(2))) _Float16 h2;
typedef __attribute__((ext_vector_type(8))) _Float16 half8;
typedef __attribute__((ext_vector_type(4))) float f32x4;
typedef unsigned short ushort;
typedef unsigned int uint;
typedef unsigned long long u64;

union H8 { uint4 q; _Float16 h[8]; h2 p[4]; };

__device__ __forceinline__ void atomAddF(float* p, float v) {
    unsafeAtomicAdd(p, v);   // HW global_atomic_add_f32
}

// ---------------- zero fill ----------------
__global__ void kzeroi(int* p, int n) {
    int i = blockIdx.x * blockDim.x + threadIdx.x;
    int stride = gridDim.x * blockDim.x;
    for (; i < n; i += stride) p[i] = 0;
}

// ---------------- CSR build ----------------
__global__ void khist(const int* __restrict__ src, const int* __restrict__ dst,
                      int* cnt_s, int* cnt_d, int ne) {
    int e = blockIdx.x * blockDim.x + threadIdx.x;
    if (e < ne) {
        atomicAdd(&cnt_s[src[e]], 1);
        atomicAdd(&cnt_d[dst[e]], 1);
    }
}

// dual-direction local scan + dinv
__global__ __launch_bounds__(256) void kscan1(
    const int* __restrict__ cnt_s, const int* __restrict__ cnt_d,
    int* off_s, int* off_d, int* bsum_s, int* bsum_d,
    float* dinv_s, float* dinv_d) {
    int dir = blockIdx.x >= NBLK;
    int lb = blockIdx.x - dir * NBLK;
    const int* cnt = dir ? cnt_d : cnt_s;
    int* off = dir ? off_d : off_s;
    int* bsum = dir ? bsum_d : bsum_s;
    float* dinv = dir ? dinv_d : dinv_s;
    __shared__ int s[256];
    int tid = threadIdx.x;
    int base = lb * SCAN_CHUNK + tid * 4;
    int v[4], sum = 0;
#pragma unroll
    for (int q = 0; q < 4; q++) {
        int c = (base + q < Nn) ? cnt[base + q] : 0;
        v[q] = c;
        sum += c;
        if (base + q < Nn) dinv[base + q] = (c > 0) ? rsqrtf((float)c) : 0.f;
    }
    s[tid] = sum;
    __syncthreads();
#pragma unroll
    for (int ofs = 1; ofs < 256; ofs <<= 1) {
        int t = (tid >= ofs) ? s[tid - ofs] : 0;
        __syncthreads();
        s[tid] += t;
        __syncthreads();
    }
    if (tid == 255) bsum[lb] = s[255];
    int run = s[tid] - sum;
#pragma unroll
    for (int q = 0; q < 4; q++) {
        if (base + q < Nn) off[base + q] = run;
        run += v[q];
    }
}

__global__ __launch_bounds__(128) void kscan2(int* bsum_s, int* bsum_d,
                                              int* off_s, int* off_d) {
    int dir = blockIdx.x;
    int* bsum = dir ? bsum_d : bsum_s;
    int* off = dir ? off_d : off_s;
    __shared__ int s[128];
    int tid = threadIdx.x;
    int v = (tid < NBLK) ? bsum[tid] : 0;
    s[tid] = v;
    __syncthreads();
#pragma unroll
    for (int ofs = 1; ofs < 128; ofs <<= 1) {
        int t = (tid >= ofs) ? s[tid - ofs] : 0;
        __syncthreads();
        s[tid] += t;
        __syncthreads();
    }
    if (tid < NBLK) bsum[tid] = s[tid] - v;
    if (tid == 127) off[Nn] = s[127];
}

__global__ void kscan3(int* off_s, int* off_d, const int* __restrict__ bsum_s,
                       const int* __restrict__ bsum_d, int* cur_s, int* cur_d) {
    int idx = blockIdx.x * blockDim.x + threadIdx.x;
    if (idx >= 2 * Nn) return;
    int dir = idx >= Nn;
    int i = idx - dir * Nn;
    int* off = dir ? off_d : off_s;
    const int* bsum = dir ? bsum_d : bsum_s;
    int* cur = dir ? cur_d : cur_s;
    int o = off[i] + bsum[i >> 10];
    off[i] = o;
    cur[i] = o;
}

// interleaved edge record: low32 = (nbr<<4)|type, high32 = norm bits
__global__ void kscatter(const int* __restrict__ src, const int* __restrict__ dst,
                         const int* __restrict__ typ,
                         const float* __restrict__ dinv_s, const float* __restrict__ dinv_d,
                         int* cur_s, int* cur_d,
                         u64* rec_s, u64* rec_d, int ne) {
    int e = blockIdx.x * blockDim.x + threadIdx.x;
    if (e >= ne) return;
    int s = src[e], d = dst[e], t = typ[e];
    int ps = atomicAdd(&cur_s[s], 1);
    rec_s[ps] = (u64)(uint)((d << 4) | t) |
                ((u64)__float_as_uint(dinv_s[s] * dinv_s[d]) << 32);
    int pd = atomicAdd(&cur_d[d], 1);
    rec_d[pd] = (u64)(uint)((s << 4) | t) |
                ((u64)__float_as_uint(dinv_d[d] * dinv_d[s]) << 32);
}

// ---------------- mega-prep: x cast | W cast (both layers) | rel chain | rel pads ------
__global__ __launch_bounds__(256) void kprep(
    const float* __restrict__ x, const float* __restrict__ lr0,
    const float* __restrict__ w_in, const float* __restrict__ w_out,
    const float* __restrict__ w_loop, const float* __restrict__ w_rel,
    const float* __restrict__ r0,
    half_t* __restrict__ xb, half_t* __restrict__ xlb,
    half_t* __restrict__ Wt, half_t* __restrict__ rel0p, half_t* __restrict__ rel1p,
    float* __restrict__ r2out) {
    int blk = blockIdx.x;
    int tid = threadIdx.x;
    if (blk < XBLK) {
        // xb = f16(x0), xlb = f16(x0 * looprel0)
        int idx = blk * 256 + tid;
        int base = idx * 8;
        int k = base & 127;
        float4 v0 = *(const float4*)(x + base);
        float4 v1 = *(const float4*)(x + base + 4);
        float4 l0 = *(const float4*)(lr0 + k);
        float4 l1 = *(const float4*)(lr0 + k + 4);
        H8 xo, xl;
        xo.h[0] = (half_t)v0.x; xo.h[1] = (half_t)v0.y; xo.h[2] = (half_t)v0.z; xo.h[3] = (half_t)v0.w;
        xo.h[4] = (half_t)v1.x; xo.h[5] = (half_t)v1.y; xo.h[6] = (half_t)v1.z; xo.h[7] = (half_t)v1.w;
        xl.h[0] = (half_t)(v0.x * l0.x); xl.h[1] = (half_t)(v0.y * l0.y);
        xl.h[2] = (half_t)(v0.z * l0.z); xl.h[3] = (half_t)(v0.w * l0.w);
        xl.h[4] = (half_t)(v1.x * l1.x); xl.h[5] = (half_t)(v1.y * l1.y);
        xl.h[6] = (half_t)(v1.z * l1.z); xl.h[7] = (half_t)(v1.w * l1.w);
        *(uint4*)(xb + base) = xo.q;
        *(uint4*)(xlb + base) = xl.q;
    } else if (blk < XBLK + 384) {
        // Wt[l][p][n][k] = f16(W[l,p][k][n]) for both layers
        int idx = (blk - XBLK) * 256 + tid;   // 0..98303
        int l = idx >= 49152;
        int rem = idx - l * 49152;
        int p = rem >> 14, ri = rem & 16383;
        int n = ri >> 7, k = ri & 127;
        const float* W = (p == 0) ? (w_in + l * 16384)
                       : ((p == 1) ? (w_out + l * 16384) : (w_loop + l * 16384));
        Wt[idx] = (half_t)W[k * 128 + n];
    } else if (blk == XBLK + 384) {
        // rel chain: rel1p = f16(r0 @ w_rel[0]) rows 0..9, pad 10..15 = 0; r2out = r1 @ w_rel[1]
        __shared__ float sr[Rr * Dd];
        for (int i = tid; i < Rr * Dd; i += 256) sr[i] = r0[i];
        __syncthreads();
        for (int ph = 0; ph < 2; ph++) {
            const float* w = w_rel + ph * 16384;
            float o[5];
#pragma unroll
            for (int q = 0; q < 5; q++) {
                int oi = tid + q * 256;
                int row = oi >> 7, j = oi & 127;
                float acc = 0.f;
                for (int k = 0; k < 128; k++) acc += sr[row * 128 + k] * w[k * 128 + j];
                o[q] = acc;
            }
            __syncthreads();
#pragma unroll
            for (int q = 0; q < 5; q++) {
                int oi = tid + q * 256;
                sr[oi] = o[q];
                if (ph == 0) rel1p[oi] = (half_t)o[q];
                else r2out[oi] = o[q];
            }
            __syncthreads();
        }
        for (int i = Rr * Dd + tid; i < 16 * Dd; i += 256) rel1p[i] = (half_t)0.f;
    } else {
        // rel0p: rows 0..9 = f16(r0), rows 10..15 = 0
        for (int i = tid; i < 16 * Dd; i += 256)
            rel0p[i] = (i < Rr * Dd) ? (half_t)r0[i] : (half_t)0.f;
    }
}

// ---------------- gather v4: 4 nodes/wave, 16B/lane, LDS rel, pk-fp16 math ----------------
__global__ __launch_bounds__(256) void kgather(
    const int* __restrict__ off_s, const u64* __restrict__ rec_s,
    const int* __restrict__ off_d, const u64* __restrict__ rec_d,
    const half_t* __restrict__ xb, const half_t* __restrict__ relp,
    half_t* __restrict__ aggin, half_t* __restrict__ aggout, int gb) {
    __shared__ uint4 sRel[256];          // 16 padded type-rows x 128 fp16 = 4 KB
    sRel[threadIdx.x] = ((const uint4*)relp)[threadIdx.x];
    __syncthreads();

    int blk = blockIdx.x;
    const int* off; const u64* rec; half_t* agg;
    if (blk < gb) { off = off_s; rec = rec_s; agg = aggin; }
    else { blk -= gb; off = off_d; rec = rec_d; agg = aggout; }
    int wv = threadIdx.x >> 6;       // wave 0..3
    int lane = threadIdx.x & 63;
    int nq = lane >> 4;              // node quarter 0..3
    int hl = lane & 15;              // 16B chunk within row
    int node = blk * 16 + wv * 4 + nq;
    bool valid = node < Nn;
    int nodec = valid ? node : (Nn - 1);
    int b = off[nodec];
    int n_it = valid ? (off[nodec + 1] - b) : 0;

    const uint4* x16 = (const uint4*)xb;
    h2 acc0 = {(half_t)0.f, (half_t)0.f}, acc1 = acc0, acc2 = acc0, acc3 = acc0;

    int it = 0;
    for (; it + 1 < n_it; it += 2) {     // per-quarter divergent loop: no wasted loads
        u64 rr0 = rec[b + it];
        u64 rr1 = rec[b + it + 1];
        uint p0 = (uint)rr0, p1 = (uint)rr1;
        H8 xv0, xv1, rv0, rv1;
        xv0.q = x16[(size_t)(p0 >> 4) * 16 + hl];
        xv1.q = x16[(size_t)(p1 >> 4) * 16 + hl];
        rv0.q = sRel[(p0 & 15u) * 16 + hl];
        rv1.q = sRel[(p1 & 15u) * 16 + hl];
        half_t w0h = (half_t)__uint_as_float((uint)(rr0 >> 32));
        half_t w1h = (half_t)__uint_as_float((uint)(rr1 >> 32));
        h2 w0 = {w0h, w0h}, w1 = {w1h, w1h};
        acc0 += (xv0.p[0] * rv0.p[0]) * w0;
        acc1 += (xv0.p[1] * rv0.p[1]) * w0;
        acc2 += (xv0.p[2] * rv0.p[2]) * w0;
        acc3 += (xv0.p[3] * rv0.p[3]) * w0;
        acc0 += (xv1.p[0] * rv1.p[0]) * w1;
        acc1 += (xv1.p[1] * rv1.p[1]) * w1;
        acc2 += (xv1.p[2] * rv1.p[2]) * w1;
        acc3 += (xv1.p[3] * rv1.p[3]) * w1;
    }
    if (it < n_it) {
        u64 rr0 = rec[b + it];
        uint p0 = (uint)rr0;
        H8 xv0, rv0;
        xv0.q = x16[(size_t)(p0 >> 4) * 16 + hl];
        rv0.q = sRel[(p0 & 15u) * 16 + hl];
        half_t w0h = (half_t)__uint_as_float((uint)(rr0 >> 32));
        h2 w0 = {w0h, w0h};
        acc0 += (xv0.p[0] * rv0.p[0]) * w0;
        acc1 += (xv0.p[1] * rv0.p[1]) * w0;
        acc2 += (xv0.p[2] * rv0.p[2]) * w0;
        acc3 += (xv0.p[3] * rv0.p[3]) * w0;
    }
    if (valid) {
        H8 o;
        o.p[0] = acc0; o.p[1] = acc1; o.p[2] = acc2; o.p[3] = acc3;
        ((uint4*)agg)[(size_t)node * 16 + hl] = o.q;
    }
}

// ---------------- MFMA GEMM + bias + BN col stats, fp16 out ----------------
__global__ __launch_bounds__(256) void kmm(
    const half_t* __restrict__ aggin, const half_t* __restrict__ aggout,
    const half_t* __restrict__ xlb, const half_t* __restrict__ Wt,
    const float* __restrict__ bias, half_t* __restrict__ out,
    float* colsum, float* colsumsq) {
    __shared__ half_t sW[128 * LDK];
    const int tid = threadIdx.x;
    const int wv = tid >> 6;
    const int lane = tid & 63;
    const int col = lane & 15;
    const int quad = lane >> 4;
    const int m0 = blockIdx.x * 128;
    const int rowbase = m0 + wv * 32;

    f32x4 acc[2][8];
#pragma unroll
    for (int m = 0; m < 2; m++)
#pragma unroll
        for (int j = 0; j < 8; j++) acc[m][j] = (f32x4){0.f, 0.f, 0.f, 0.f};

    const half_t* Ap[3] = {aggin, aggout, xlb};
    int r0 = rowbase + col;
    int r1 = r0 + 16;
    int r0c = (r0 < Nn) ? r0 : (Nn - 1);
    int r1c = (r1 < Nn) ? r1 : (Nn - 1);

    for (int p = 0; p < 3; p++) {
        __syncthreads();
        {
            const half8* Wg = (const half8*)(Wt + p * 16384);
#pragma unroll
            for (int i = 0; i < 8; i++) {
                int c = tid + i * 256;
                int n = c >> 4, ko = (c & 15) * 8;
                *(half8*)(sW + n * LDK + ko) = Wg[c];
            }
        }
        __syncthreads();
        const half_t* A = Ap[p];
#pragma unroll
        for (int s = 0; s < 4; s++) {
            int ko = s * 32 + quad * 8;
            half8 va0 = *(const half8*)(A + r0c * Dd + ko);
            half8 va1 = *(const half8*)(A + r1c * Dd + ko);
#pragma unroll
            for (int j = 0; j < 8; j++) {
                half8 vb = *(const half8*)(sW + (j * 16 + col) * LDK + ko);
                acc[0][j] = __builtin_amdgcn_mfma_f32_16x16x32_f16(va0, vb, acc[0][j], 0, 0, 0);
                acc[1][j] = __builtin_amdgcn_mfma_f32_16x16x32_f16(va1, vb, acc[1][j], 0, 0, 0);
            }
        }
    }

    const float inv3 = 1.f / 3.f;
    float bcol[8], sum[8], ssq[8];
#pragma unroll
    for (int j = 0; j < 8; j++) {
        bcol[j] = bias[j * 16 + col];
        sum[j] = 0.f; ssq[j] = 0.f;
    }
#pragma unroll
    for (int m = 0; m < 2; m++) {
        int rb = rowbase + m * 16;
        if (rb < Nn) {
#pragma unroll
            for (int j = 0; j < 8; j++) {
#pragma unroll
                for (int r = 0; r < 4; r++) {
                    float v = acc[m][j][r] * inv3 + bcol[j];
                    out[(rb + quad * 4 + r) * Dd + j * 16 + col] = (half_t)v;
                    sum[j] += v;
                    ssq[j] += v * v;
                }
            }
        }
    }
#pragma unroll
    for (int j = 0; j < 8; j++) {
        sum[j] += __shfl_xor(sum[j], 16, 64);
        sum[j] += __shfl_xor(sum[j], 32, 64);
        ssq[j] += __shfl_xor(ssq[j], 16, 64);
        ssq[j] += __shfl_xor(ssq[j], 32, 64);
    }
    __syncthreads();
    float* sred = (float*)sW;
    if (quad == 0) {
#pragma unroll
        for (int j = 0; j < 8; j++) {
            sred[wv * 128 + j * 16 + col] = sum[j];
            sred[512 + wv * 128 + j * 16 + col] = ssq[j];
        }
    }
    __syncthreads();
    if (tid < 128) {
        float s = 0.f, s2 = 0.f;
#pragma unroll
        for (int w = 0; w < 4; w++) {
            s += sred[w * 128 + tid];
            s2 += sred[512 + w * 128 + tid];
        }
        atomAddF(&colsum[tid], s);
        atomAddF(&colsumsq[tid], s2);
    }
}

// ---------------- norm+tanh layer0 (stats inline): write fp16 xb, xlb ----------------
__global__ __launch_bounds__(256) void knorm0(const half_t* __restrict__ outh,
                                              const float* __restrict__ colsum,
                                              const float* __restrict__ colsumsq,
                                              const float* __restrict__ lr,
                                              half_t* __restrict__ xb,
                                              half_t* __restrict__ xlb) {
    __shared__ float sm[128], srs[128];
    int tid = threadIdx.x;
    if (tid < 128) {
        float m = colsum[tid] * (1.f / (float)Nn);
        float v = colsumsq[tid] * (1.f / (float)Nn) - m * m;
        sm[tid] = m;
        srs[tid] = rsqrtf(v + EPSF);
    }
    __syncthreads();
    int idx = blockIdx.x * 256 + tid;
    int base = idx * 8;
    int k = base & 127;
    H8 v; v.q = *(const uint4*)(outh + base);
    H8 xo, xl;
#pragma unroll
    for (int q = 0; q < 8; q++) {
        float t = tanhf(((float)v.h[q] - sm[k + q]) * srs[k + q]);
        xo.h[q] = (half_t)t;
        xl.h[q] = (half_t)(t * lr[k + q]);
    }
    *(uint4*)(xb + base) = xo.q;
    *(uint4*)(xlb + base) = xl.q;
}

// ---------------- norm+tanh layer1 (stats inline): write fp32 final ----------------
__global__ __launch_bounds__(256) void knorm1(const half_t* __restrict__ outh,
                                              const float* __restrict__ colsum,
                                              const float* __restrict__ colsumsq,
                                              float* __restrict__ xn) {
    __shared__ float sm[128], srs[128];
    int tid = threadIdx.x;
    if (tid < 128) {
        float m = colsum[tid] * (1.f / (float)Nn);
        float v = colsumsq[tid] * (1.f / (float)Nn) - m * m;
        sm[tid] = m;
        srs[tid] = rsqrtf(v + EPSF);
    }
    __syncthreads();
    int idx = blockIdx.x * 256 + tid;
    int base = idx * 8;
    int k = base & 127;
    H8 v; v.q = *(const uint4*)(outh + base);
    float4 o0, o1;
    o0.x = tanhf(((float)v.h[0] - sm[k + 0]) * srs[k + 0]);
    o0.y = tanhf(((float)v.h[1] - sm[k + 1]) * srs[k + 1]);
    o0.z = tanhf(((float)v.h[2] - sm[k + 2]) * srs[k + 2]);
    o0.w = tanhf(((float)v.h[3] - sm[k + 3]) * srs[k + 3]);
    o1.x = tanhf(((float)v.h[4] - sm[k + 4]) * srs[k + 4]);
    o1.y = tanhf(((float)v.h[5] - sm[k + 5]) * srs[k + 5]);
    o1.z = tanhf(((float)v.h[6] - sm[k + 6]) * srs[k + 6]);
    o1.w = tanhf(((float)v.h[7] - sm[k + 7]) * srs[k + 7]);
    *(float4*)(xn + base) = o0;
    *(float4*)(xn + base + 4) = o1;
}

extern "C" void kernel_launch(void* const* d_in, const int* in_sizes, int n_in,
                              void* d_out, int out_size, void* d_ws, size_t ws_size,
                              hipStream_t stream) {
    const float* x0      = (const float*)d_in[0];
    const float* r0      = (const float*)d_in[1];
    const float* w_in    = (const float*)d_in[2];
    const float* w_out   = (const float*)d_in[3];
    const float* w_loop  = (const float*)d_in[4];
    const float* w_rel   = (const float*)d_in[5];
    const float* looprel = (const float*)d_in[6];
    const float* bias    = (const float*)d_in[7];
    const int* esrc = (const int*)d_in[8];
    const int* edst = (const int*)d_in[9];
    const int* etyp = (const int*)d_in[10];
    float* outp = (float*)d_out;

    // half region (16B-aligned base)
    half_t* us = (half_t*)d_ws;
    half_t* aggin_h  = us;                        // ND
    half_t* aggout_h = us + (size_t)ND;           // ND
    half_t* xb       = us + 2 * (size_t)ND;       // ND
    half_t* xlb      = us + 3 * (size_t)ND;       // ND
    half_t* outh     = us + 4 * (size_t)ND;       // ND
    half_t* Wt       = us + 5 * (size_t)ND;       // 2*49152
    half_t* rel0p    = Wt + 2 * 49152;            // 16*128
    half_t* rel1p    = rel0p + 16 * Dd;           // 16*128
    // u64 records (8B-aligned)
    u64* rec_s = (u64*)(rel1p + 16 * Dd);         // Ee+64
    u64* rec_d = rec_s + (Ee + 64);               // Ee+64
    // float region
    float* fp = (float*)(rec_d + (Ee + 64));
    float* dinv_s  = fp;   fp += Nn;
    float* dinv_d  = fp;   fp += Nn;
    // int region (zero block: cnt_s, cnt_d, colsums A+B contiguous)
    int* ip = (int*)fp;
    int* cnt_s  = ip;  ip += Nn;
    int* cnt_d  = ip;  ip += Nn;
    float* colsumA = (float*)ip;  ip += 2 * Dd;
    float* colsumB = (float*)ip;  ip += 2 * Dd;
    int* off_s  = ip;  ip += Nn + 1;
    int* off_d  = ip;  ip += Nn + 1;
    int* cur_s  = ip;  ip += Nn;
    int* cur_d  = ip;  ip += Nn;
    int* bsum_s = ip;  ip += 128;
    int* bsum_d = ip;  ip += 128;

    // 1: zero cnt_s+cnt_d+colsumA+colsumB
    kzeroi<<<256, 256, 0, stream>>>(cnt_s, 2 * Nn + 4 * Dd);
    // 2: histogram
    khist<<<(Ee + 255) / 256, 256, 0, stream>>>(esrc, edst, cnt_s, cnt_d, Ee);
    // 3-5: dual scans (+dinv, +cursor copy)
    kscan1<<<2 * NBLK, 256, 0, stream>>>(cnt_s, cnt_d, off_s, off_d, bsum_s, bsum_d,
                                         dinv_s, dinv_d);
    kscan2<<<2, 128, 0, stream>>>(bsum_s, bsum_d, off_s, off_d);
    kscan3<<<(2 * Nn + 255) / 256, 256, 0, stream>>>(off_s, off_d, bsum_s, bsum_d,
                                                     cur_s, cur_d);
    // 6: CSR scatter (interleaved u64 records)
    kscatter<<<(Ee + 255) / 256, 256, 0, stream>>>(esrc, edst, etyp, dinv_s, dinv_d,
                                                   cur_s, cur_d, rec_s, rec_d, Ee);
    // 7: mega-prep
    kprep<<<XBLK + 384 + 2, 256, 0, stream>>>(
        x0, looprel, w_in, w_out, w_loop, w_rel, r0,
        xb, xlb, Wt, rel0p, rel1p, outp + (size_t)ND);

    const int gb = (Nn + 15) / 16;
    for (int l = 0; l < 2; l++) {
        const half_t* relp = l ? rel1p : rel0p;
        float* cs = l ? colsumB : colsumA;
        kgather<<<2 * gb, 256, 0, stream>>>(off_s, rec_s, off_d, rec_d,
                                            xb, relp, aggin_h, aggout_h, gb);
        kmm<<<(Nn + 127) / 128, 256, 0, stream>>>(aggin_h, aggout_h, xlb, Wt + l * 49152,
                                                  bias + l * Dd, outh, cs, cs + Dd);
        if (l == 0) {
            knorm0<<<ND / 8 / 256, 256, 0, stream>>>(outh, cs, cs + Dd, looprel + Dd, xb, xlb);
        } else {
            knorm1<<<ND / 8 / 256, 256, 0, stream>>>(outh, cs, cs + Dd, outp);
        }
    }
}